// Round 7
// baseline (2110.059 us; speedup 1.0000x reference)
//
#include <hip/hip_runtime.h>

#define HID 64
#define LL 16
#define NLAYERS 4
#define NN 50000
#define NE 200000
#define PRR 1600000
#define DDIM 100000        // PRR / LL
#define N2P_CNT PRR
#define E2P_CNT (PRR / 2)
#define POOL_CNT DDIM
#define TOTENT (N2P_CNT + E2P_CNT + POOL_CNT)   // 2.5M
#define NBINS (DDIM + NN)                        // 150000
#define HSRC_ROWS (NN + 16)                      // + 4 bond rows per layer
#define NGRP 5
#define EBLOCKS 1250       // DDIM / (16*NGRP)

typedef __attribute__((ext_vector_type(8))) short bf16x8;
typedef __attribute__((ext_vector_type(4))) float f32x4;

__device__ __forceinline__ unsigned short f2bf(float x) {
    unsigned u = __float_as_uint(x);
    unsigned r = (u + 0x7fffu + ((u >> 16) & 1u)) >> 16;
    return (unsigned short)r;
}
__device__ __forceinline__ float bf2f(unsigned short v) {
    return __uint_as_float((unsigned)v << 16);
}

// ======================= CSR build (once per call) ==========================
__global__ void k_zero_i(int* __restrict__ b, int n) {
    int t = blockIdx.x * blockDim.x + threadIdx.x;
    if (t < n) b[t] = 0;
}
__global__ void k_set_term(int* __restrict__ start_all) {
    start_all[NBINS] = TOTENT;
}

__global__ void k_hist_all(const int* __restrict__ n2p_rows,
                           const int* __restrict__ e2p_rows,
                           const int* __restrict__ pool_rows,
                           int* __restrict__ cnt, int* __restrict__ rank_all) {
    int k = blockIdx.x * blockDim.x + threadIdx.x;
    if (k >= TOTENT) return;
    int bin;
    if (k < N2P_CNT) {
        bin = n2p_rows[k] >> 4;
    } else if (k < N2P_CNT + E2P_CNT) {
        bin = e2p_rows[k - N2P_CNT] >> 4;
    } else {
        bin = DDIM + pool_rows[k - N2P_CNT - E2P_CNT];
    }
    rank_all[k] = atomicAdd(&cnt[bin], 1);
}

__global__ void __launch_bounds__(256) k_scan_block(const int* __restrict__ cnt,
                                                    int* __restrict__ excl,
                                                    int* __restrict__ partial, int B) {
    __shared__ int lds[1024];
    int tid = threadIdx.x;
    int base = blockIdx.x * 1024;
    int self[4];
    #pragma unroll
    for (int r = 0; r < 4; ++r) {
        int i = r * 256 + tid;
        self[r] = (base + i < B) ? cnt[base + i] : 0;
        lds[i] = self[r];
    }
    __syncthreads();
    for (int off = 1; off < 1024; off <<= 1) {
        int v[4];
        #pragma unroll
        for (int r = 0; r < 4; ++r) {
            int i = r * 256 + tid;
            v[r] = (i >= off) ? lds[i - off] : 0;
        }
        __syncthreads();
        #pragma unroll
        for (int r = 0; r < 4; ++r) lds[r * 256 + tid] += v[r];
        __syncthreads();
    }
    #pragma unroll
    for (int r = 0; r < 4; ++r) {
        int i = r * 256 + tid;
        if (base + i < B) excl[base + i] = lds[i] - self[r];
    }
    if (tid == 0) partial[blockIdx.x] = lds[1023];
}

__global__ void k_scan_partial(int* __restrict__ partial, int nb) {
    if (threadIdx.x == 0) {
        int run = 0;
        for (int i = 0; i < nb; ++i) { int v = partial[i]; partial[i] = run; run += v; }
    }
}

__global__ void k_scan_add(int* __restrict__ excl, const int* __restrict__ partial, int B) {
    int i = blockIdx.x * blockDim.x + threadIdx.x;
    if (i < B) excl[i] += partial[i >> 10];
}

// unified fill: q-bins payload = src_row*16 + a  (src_row: n for n2p, NN+ty for e2p,
// gather adds layer*4 for rows >= NN); pool payload = d col.
__global__ void k_fill_all(const int* __restrict__ n2p_rows, const int* __restrict__ n2p_cols,
                           const float* __restrict__ n2p_vals,
                           const int* __restrict__ e2p_rows, const int* __restrict__ e2p_cols,
                           const float* __restrict__ e2p_vals,
                           const int* __restrict__ pool_rows, const int* __restrict__ pool_cols,
                           const float* __restrict__ pool_vals,
                           const int* __restrict__ edge_feat,
                           const int* __restrict__ start_all, const int* __restrict__ rank_all,
                           uint2* __restrict__ ent_all) {
    int k = blockIdx.x * blockDim.x + threadIdx.x;
    if (k >= TOTENT) return;
    int bin; unsigned pay; float val;
    if (k < N2P_CNT) {
        int r = n2p_rows[k];
        bin = r >> 4;
        pay = (unsigned)n2p_cols[k] * 16u + (unsigned)(r & 15);
        val = n2p_vals[k];
    } else if (k < N2P_CNT + E2P_CNT) {
        int kk = k - N2P_CNT;
        int r = e2p_rows[kk];
        bin = r >> 4;
        pay = (unsigned)(NN + edge_feat[e2p_cols[kk]]) * 16u + (unsigned)(r & 15);
        val = e2p_vals[kk];
    } else {
        int kk = k - N2P_CNT - E2P_CNT;
        bin = DDIM + pool_rows[kk];
        pay = (unsigned)pool_cols[kk];
        val = pool_vals[kk];
    }
    ent_all[start_all[bin] + rank_all[k]] = make_uint2(pay, __float_as_uint(val));
}

// ===================== upfront prep for ALL layers ==========================
#define WTBE_SZ (HID * LL * HID)    // 65536: [c][k=a*64+b] bf16
#define D1WT_SZ (128 * HID)         // 8192
#define PER_LAYER (WTBE_SZ + D1WT_SZ)

__global__ void k_prep_all(const float* __restrict__ weights,
                           const float* __restrict__ deg1_w,
                           unsigned short* __restrict__ wtBe2_all,
                           float* __restrict__ d1wT_all) {
    int t = blockIdx.x * blockDim.x + threadIdx.x;
    if (t >= NLAYERS * PER_LAYER) return;
    int i = t / PER_LAYER;
    int u = t % PER_LAYER;
    if (u < WTBE_SZ) {
        int c = u >> 10, k = u & 1023;
        int a = k >> 6, b = k & 63;
        wtBe2_all[(size_t)i * WTBE_SZ + u] =
            f2bf(weights[(size_t)i * WTBE_SZ + (b * HID + c) * LL + a]);
    } else {
        int v = u - WTBE_SZ;
        int c = v & 63, j = v >> 6;
        d1wT_all[i * D1WT_SZ + v] = deg1_w[(size_t)i * D1WT_SZ + c * 128 + j];
    }
}

// ============================ per-layer kernels =============================
// hsrc[n][c] = bf16(atom_emb[node_feat[n],c]); tail 16 rows = bond_emb (all layers)
__global__ void k_init_h(const int* __restrict__ node_feat,
                         const float* __restrict__ atom_emb,
                         const float* __restrict__ bond_emb,
                         unsigned short* __restrict__ hsrc) {
    int t = blockIdx.x * blockDim.x + threadIdx.x;
    if (t >= HSRC_ROWS * HID) return;
    int n = t >> 6, c = t & 63;
    float v = (n < NN) ? atom_emb[node_feat[n] * HID + c]
                       : bond_emb[(n - NN) * HID + c];   // bond_emb is [16][64] flat
    hsrc[t] = f2bf(v);
}

// ===== gather p (16 d's in LDS, f32) + MFMA einsum + bias + relu ============
// block: 256 thr, NGRP groups of 16 d's; wave w holds B-frags for cols [w*16,w*16+16)
__global__ void __launch_bounds__(256) k_perm_einsum(
        const int* __restrict__ qstart, const uint2* __restrict__ ent,
        const unsigned short* __restrict__ hsrc,
        const unsigned short* __restrict__ wtBe2,
        const float* __restrict__ bias_i, int loff,
        float* __restrict__ qrelu) {
    __shared__ float p_lds[16][1024];   // 64 KB
    int tid = threadIdx.x;
    int wave = tid >> 6, lane = tid & 63;
    int col = lane & 15, kgrp = lane >> 4;

    // preload B fragments (32 x 16B = 128 VGPRs), reused across all groups
    bf16x8 Bf[32];
    const unsigned short* bbase = wtBe2 + ((size_t)(wave * 16 + col)) * 1024 + kgrp * 8;
    #pragma unroll
    for (int ks = 0; ks < 32; ++ks)
        Bf[ks] = *(const bf16x8*)(bbase + ks * 32);
    float bc = bias_i[wave * 16 + col];

    for (int grp = 0; grp < NGRP; ++grp) {
        int dbase = blockIdx.x * (16 * NGRP) + grp * 16;
        __syncthreads();   // prior einsum reads done before zeroing
        for (int i = tid; i < 16 * 1024; i += 256) ((float*)p_lds)[i] = 0.f;
        __syncthreads();

        // gather: wave owns dd = wave*4 .. wave*4+3
        #pragma unroll
        for (int ii = 0; ii < 4; ++ii) {
            int dd = wave * 4 + ii;
            int d = dbase + dd;
            float* prow = &p_lds[dd][0];
            int j = qstart[d], je = qstart[d + 1];
            for (; j + 3 < je; j += 4) {
                uint2 e0 = ent[j], e1 = ent[j + 1], e2 = ent[j + 2], e3 = ent[j + 3];
                unsigned s0 = e0.x >> 4; if (s0 >= NN) s0 += loff;
                unsigned s1 = e1.x >> 4; if (s1 >= NN) s1 += loff;
                unsigned s2 = e2.x >> 4; if (s2 >= NN) s2 += loff;
                unsigned s3 = e3.x >> 4; if (s3 >= NN) s3 += loff;
                float h0 = bf2f(hsrc[(size_t)s0 * HID + lane]);
                float h1 = bf2f(hsrc[(size_t)s1 * HID + lane]);
                float h2 = bf2f(hsrc[(size_t)s2 * HID + lane]);
                float h3 = bf2f(hsrc[(size_t)s3 * HID + lane]);
                prow[(e0.x & 15) * HID + lane] += __uint_as_float(e0.y) * h0;
                prow[(e1.x & 15) * HID + lane] += __uint_as_float(e1.y) * h1;
                prow[(e2.x & 15) * HID + lane] += __uint_as_float(e2.y) * h2;
                prow[(e3.x & 15) * HID + lane] += __uint_as_float(e3.y) * h3;
            }
            for (; j < je; ++j) {
                uint2 e0 = ent[j];
                unsigned s0 = e0.x >> 4; if (s0 >= NN) s0 += loff;
                float h0 = bf2f(hsrc[(size_t)s0 * HID + lane]);
                prow[(e0.x & 15) * HID + lane] += __uint_as_float(e0.y) * h0;
            }
        }
        __syncthreads();

        // einsum: q[dbase+m][wave*16+col] = sum_k p[m][k] * W[k][col]
        f32x4 acc = {0.f, 0.f, 0.f, 0.f};
        #pragma unroll
        for (int ks = 0; ks < 32; ++ks) {
            const float* ap = &p_lds[col][ks * 32 + kgrp * 8];
            float4 lo = *(const float4*)ap;
            float4 hi = *(const float4*)(ap + 4);
            bf16x8 Af;
            Af[0] = (short)f2bf(lo.x); Af[1] = (short)f2bf(lo.y);
            Af[2] = (short)f2bf(lo.z); Af[3] = (short)f2bf(lo.w);
            Af[4] = (short)f2bf(hi.x); Af[5] = (short)f2bf(hi.y);
            Af[6] = (short)f2bf(hi.z); Af[7] = (short)f2bf(hi.w);
            acc = __builtin_amdgcn_mfma_f32_16x16x32_bf16(Af, Bf[ks], acc, 0, 0, 0);
        }
        #pragma unroll
        for (int r = 0; r < 4; ++r)
            qrelu[(size_t)(dbase + kgrp * 4 + r) * HID + wave * 16 + col] =
                fmaxf(acc[r] + bc, 0.f);
    }
}

// ===== pool-gather + degree gate (round-5 proven shape), h out bf16 =========
__global__ void __launch_bounds__(256) k_pool_gate(
        const int* __restrict__ pstart, const uint2* __restrict__ ent,
        const float* __restrict__ qrelu, const float* __restrict__ degs,
        const float* __restrict__ d0w, const float* __restrict__ d0b,
        const float* __restrict__ d1wT, const float* __restrict__ d1b,
        unsigned short* __restrict__ hsrc) {
    int wid = (blockIdx.x * 256 + threadIdx.x) >> 6;
    if (wid >= NN) return;
    int c = threadIdx.x & 63;
    float acc0 = 0.f, acc1 = 0.f;
    int j = pstart[wid], e = pstart[wid + 1];
    for (; j + 1 < e; j += 2) {
        uint2 e0 = ent[j], e1 = ent[j + 1];
        acc0 += __uint_as_float(e0.y) * qrelu[(size_t)e0.x * HID + c];
        acc1 += __uint_as_float(e1.y) * qrelu[(size_t)e1.x * HID + c];
    }
    if (j < e) {
        uint2 e0 = ent[j];
        acc0 += __uint_as_float(e0.y) * qrelu[(size_t)e0.x * HID + c];
    }
    float acc = acc0 + acc1;
    float deg = degs[wid];
    float rv0 = fmaxf(deg * d0w[c]      + d0b[c],      0.f);
    float rv1 = fmaxf(deg * d0w[64 + c] + d0b[64 + c], 0.f);
    float gf = d1b[c];
    #pragma unroll 8
    for (int j2 = 0; j2 < 64; ++j2) {
        float f0 = __shfl(rv0, j2, 64);
        float f1 = __shfl(rv1, j2, 64);
        gf += d1wT[j2 * HID + c] * f0 + d1wT[(64 + j2) * HID + c] * f1;
    }
    hsrc[(size_t)wid * HID + c] = f2bf(acc * gf);
}

// ============================== epilogue ====================================
__global__ void k_reduce(const unsigned short* __restrict__ hsrc,
                         float* __restrict__ partial_red) {
    __shared__ float lds[256];
    int tid = threadIdx.x;
    float s = 0.f;
    for (int idx = blockIdx.x * 256 + tid; idx < NN * HID; idx += gridDim.x * 256)
        s += bf2f(hsrc[idx]);
    lds[tid] = s;
    __syncthreads();
    if (tid < 64)
        partial_red[blockIdx.x * 64 + tid] = lds[tid] + lds[tid + 64] + lds[tid + 128] + lds[tid + 192];
}

__global__ void k_final(const float* __restrict__ partial_red,
                        const float* __restrict__ fw,
                        const float* __restrict__ fb, float* __restrict__ out) {
    int lane = threadIdx.x;
    float s = 0.f;
    for (int b = 0; b < 256; ++b) s += partial_red[b * 64 + lane];
    float v = s * (1.0f / NN) * fw[lane];
    for (int off = 32; off; off >>= 1) v += __shfl_down(v, off, 64);
    if (lane == 0) out[0] = v + fb[0];
}

// ============================================================================
extern "C" void kernel_launch(void* const* d_in, const int* in_sizes, int n_in,
                              void* d_out, int out_size, void* d_ws, size_t ws_size,
                              hipStream_t stream) {
    const int*   node_feat = (const int*)d_in[0];
    const int*   edge_feat = (const int*)d_in[1];
    const float* degs      = (const float*)d_in[2];
    const int*   n2p_rows  = (const int*)d_in[3];
    const int*   n2p_cols  = (const int*)d_in[4];
    const float* n2p_vals  = (const float*)d_in[5];
    const int*   e2p_rows  = (const int*)d_in[6];
    const int*   e2p_cols  = (const int*)d_in[7];
    const float* e2p_vals  = (const float*)d_in[8];
    const int*   pool_rows = (const int*)d_in[9];
    const int*   pool_cols = (const int*)d_in[10];
    const float* pool_vals = (const float*)d_in[11];
    const float* atom_emb  = (const float*)d_in[13];
    const float* bond_emb  = (const float*)d_in[14];  // [4,4,64] = [16][64]
    const float* weights   = (const float*)d_in[15];
    const float* bias      = (const float*)d_in[16];
    const float* deg0_w    = (const float*)d_in[17];
    const float* deg0_b    = (const float*)d_in[18];
    const float* deg1_w    = (const float*)d_in[19];
    const float* deg1_b    = (const float*)d_in[20];
    const float* final_w   = (const float*)d_in[21];
    const float* final_b   = (const float*)d_in[22];
    float* out = (float*)d_out;

    char* wsb = (char*)d_ws;
    size_t off = 0;
    auto alloc = [&](size_t bytes) -> void* {
        void* ptr = wsb + off;
        off += (bytes + 255) & ~(size_t)255;
        return ptr;
    };
    unsigned short* hsrc     = (unsigned short*)alloc((size_t)HSRC_ROWS * HID * 2); // 6.4 MB
    float*          qrelu    = (float*)alloc((size_t)DDIM * HID * 4);               // 25.6 MB
    unsigned short* wtBe2_all= (unsigned short*)alloc((size_t)NLAYERS * WTBE_SZ * 2);
    float*          d1wT_all = (float*)alloc((size_t)NLAYERS * D1WT_SZ * 4);
    float*          partial_red = (float*)alloc(256 * 64 * 4);
    int*   start_all = (int*)alloc((size_t)(NBINS + 1) * 4);
    int*   cnt       = (int*)alloc((size_t)NBINS * 4);
    int*   partial   = (int*)alloc(512 * 4);
    int*   rank_all  = (int*)alloc((size_t)TOTENT * 4);     // 10 MB
    uint2* ent_all   = (uint2*)alloc((size_t)TOTENT * 8);   // 20 MB

    // ---------------- CSR build (shared across layers) ----------------------
    k_zero_i<<<(NBINS + 255) / 256, 256, 0, stream>>>(cnt, NBINS);
    k_hist_all<<<(TOTENT + 255) / 256, 256, 0, stream>>>(n2p_rows, e2p_rows, pool_rows,
                                                         cnt, rank_all);
    k_scan_block<<<(NBINS + 1023) / 1024, 256, 0, stream>>>(cnt, start_all, partial, NBINS);
    k_scan_partial<<<1, 64, 0, stream>>>(partial, (NBINS + 1023) / 1024);
    k_scan_add<<<(NBINS + 255) / 256, 256, 0, stream>>>(start_all, partial, NBINS);
    k_set_term<<<1, 1, 0, stream>>>(start_all);
    k_fill_all<<<(TOTENT + 255) / 256, 256, 0, stream>>>(n2p_rows, n2p_cols, n2p_vals,
                                                         e2p_rows, e2p_cols, e2p_vals,
                                                         pool_rows, pool_cols, pool_vals,
                                                         edge_feat, start_all, rank_all, ent_all);

    // ---------------- prep + init -------------------------------------------
    k_prep_all<<<(NLAYERS * PER_LAYER + 255) / 256, 256, 0, stream>>>(
        weights, deg1_w, wtBe2_all, d1wT_all);
    k_init_h<<<(HSRC_ROWS * HID + 255) / 256, 256, 0, stream>>>(
        node_feat, atom_emb, bond_emb, hsrc);

    // ---------------- layers ------------------------------------------------
    for (int i = 0; i < NLAYERS; ++i) {
        k_perm_einsum<<<EBLOCKS, 256, 0, stream>>>(
            start_all, ent_all, hsrc,
            wtBe2_all + (size_t)i * WTBE_SZ, bias + i * HID, i * 4, qrelu);
        k_pool_gate<<<(NN + 3) / 4, 256, 0, stream>>>(
            start_all + DDIM, ent_all, qrelu, degs,
            deg0_w + i * 2 * HID, deg0_b + i * 2 * HID,
            d1wT_all + (size_t)i * D1WT_SZ, deg1_b + i * HID, hsrc);
    }

    k_reduce<<<256, 256, 0, stream>>>(hsrc, partial_red);
    k_final<<<1, 64, 0, stream>>>(partial_red, final_w, final_b, out);
}

// Round 8
// 954.120 us; speedup vs baseline: 2.2115x; 2.2115x over previous
//
#include <hip/hip_runtime.h>

#define HID 64
#define LL 16
#define NLAYERS 4
#define NN 50000
#define NE 200000
#define PRR 1600000
#define DDIM 100000        // PRR / LL
#define MGRPS 3125         // NN / 16
#define GE_BASE 800000     // ge rows appended to g after NN*16 rows
#define GROWS 800064
#define N2P_CNT PRR
#define E2P_CNT (PRR / 2)
#define POOL_CNT DDIM
#define TOTENT (N2P_CNT + E2P_CNT + POOL_CNT)   // 2.5M
#define NBINS (DDIM + NN)                        // 150000
#define GEMM_BLOCKS 196    // ceil(3125/16); block GEMM_BLOCKS does ge tail copy

typedef __attribute__((ext_vector_type(8))) short bf16x8;
typedef __attribute__((ext_vector_type(4))) float f32x4;

__device__ __forceinline__ unsigned short f2bf(float x) {
    unsigned u = __float_as_uint(x);
    unsigned r = (u + 0x7fffu + ((u >> 16) & 1u)) >> 16;
    return (unsigned short)r;
}
__device__ __forceinline__ float bf2f(unsigned short v) {
    return __uint_as_float((unsigned)v << 16);
}

// ======================= CSR build (once per call) ==========================
__global__ void k_zero_i(int* __restrict__ b, int n) {
    int t = blockIdx.x * blockDim.x + threadIdx.x;
    if (t < n) b[t] = 0;
}
__global__ void k_set_term(int* __restrict__ start_all) {
    start_all[NBINS] = TOTENT;
}

__global__ void k_hist_all(const int* __restrict__ n2p_rows,
                           const int* __restrict__ e2p_rows,
                           const int* __restrict__ pool_rows,
                           int* __restrict__ cnt, int* __restrict__ rank_all) {
    int k = blockIdx.x * blockDim.x + threadIdx.x;
    if (k >= TOTENT) return;
    int bin;
    if (k < N2P_CNT) {
        bin = n2p_rows[k] >> 4;
    } else if (k < N2P_CNT + E2P_CNT) {
        bin = e2p_rows[k - N2P_CNT] >> 4;
    } else {
        bin = DDIM + pool_rows[k - N2P_CNT - E2P_CNT];
    }
    rank_all[k] = atomicAdd(&cnt[bin], 1);
}

__global__ void __launch_bounds__(256) k_scan_block(const int* __restrict__ cnt,
                                                    int* __restrict__ excl,
                                                    int* __restrict__ partial, int B) {
    __shared__ int lds[1024];
    int tid = threadIdx.x;
    int base = blockIdx.x * 1024;
    int self[4];
    #pragma unroll
    for (int r = 0; r < 4; ++r) {
        int i = r * 256 + tid;
        self[r] = (base + i < B) ? cnt[base + i] : 0;
        lds[i] = self[r];
    }
    __syncthreads();
    for (int off = 1; off < 1024; off <<= 1) {
        int v[4];
        #pragma unroll
        for (int r = 0; r < 4; ++r) {
            int i = r * 256 + tid;
            v[r] = (i >= off) ? lds[i - off] : 0;
        }
        __syncthreads();
        #pragma unroll
        for (int r = 0; r < 4; ++r) lds[r * 256 + tid] += v[r];
        __syncthreads();
    }
    #pragma unroll
    for (int r = 0; r < 4; ++r) {
        int i = r * 256 + tid;
        if (base + i < B) excl[base + i] = lds[i] - self[r];
    }
    if (tid == 0) partial[blockIdx.x] = lds[1023];
}

__global__ void k_scan_partial(int* __restrict__ partial, int nb) {
    if (threadIdx.x == 0) {
        int run = 0;
        for (int i = 0; i < nb; ++i) { int v = partial[i]; partial[i] = run; run += v; }
    }
}

__global__ void k_scan_add(int* __restrict__ excl, const int* __restrict__ partial, int B) {
    int i = blockIdx.x * blockDim.x + threadIdx.x;
    if (i < B) excl[i] += partial[i >> 10];
}

// unified fill: q-bin payload = g row index (cols*16+a, or GE_BASE+ef*16+a);
// pool-bin payload = d column.
__global__ void k_fill_all(const int* __restrict__ n2p_rows, const int* __restrict__ n2p_cols,
                           const float* __restrict__ n2p_vals,
                           const int* __restrict__ e2p_rows, const int* __restrict__ e2p_cols,
                           const float* __restrict__ e2p_vals,
                           const int* __restrict__ pool_rows, const int* __restrict__ pool_cols,
                           const float* __restrict__ pool_vals,
                           const int* __restrict__ edge_feat,
                           const int* __restrict__ start_all, const int* __restrict__ rank_all,
                           uint2* __restrict__ ent_all) {
    int k = blockIdx.x * blockDim.x + threadIdx.x;
    if (k >= TOTENT) return;
    int bin; unsigned pay; float val;
    if (k < N2P_CNT) {
        int r = n2p_rows[k];
        bin = r >> 4;
        pay = (unsigned)n2p_cols[k] * 16u + (unsigned)(r & 15);
        val = n2p_vals[k];
    } else if (k < N2P_CNT + E2P_CNT) {
        int kk = k - N2P_CNT;
        int r = e2p_rows[kk];
        bin = r >> 4;
        pay = (unsigned)GE_BASE + (unsigned)edge_feat[e2p_cols[kk]] * 16u + (unsigned)(r & 15);
        val = e2p_vals[kk];
    } else {
        int kk = k - N2P_CNT - E2P_CNT;
        bin = DDIM + pool_rows[kk];
        pay = (unsigned)pool_cols[kk];
        val = pool_vals[kk];
    }
    ent_all[start_all[bin] + rank_all[k]] = make_uint2(pay, __float_as_uint(val));
}

// ===================== upfront prep for ALL layers ==========================
#define WTB_SZ (LL * HID * HID)     // 65536
#define D1WT_SZ (128 * HID)         // 8192
#define GE_SZ (4 * LL * HID)        // 4096
#define PER_LAYER (WTB_SZ + D1WT_SZ + GE_SZ)   // 77824

__global__ void k_prep_all(const float* __restrict__ weights,
                           const float* __restrict__ bond_emb,
                           const float* __restrict__ deg1_w,
                           unsigned short* __restrict__ wtB_all,
                           float* __restrict__ d1wT_all,
                           float* __restrict__ ge_all) {
    int t = blockIdx.x * blockDim.x + threadIdx.x;
    if (t >= NLAYERS * PER_LAYER) return;
    int i = t / PER_LAYER;
    int u = t % PER_LAYER;
    const float* w_i = weights + (size_t)i * WTB_SZ;
    if (u < WTB_SZ) {
        int b = u & 63, N = u >> 6;
        int a = N >> 6, c = N & 63;
        wtB_all[(size_t)i * WTB_SZ + u] = f2bf(w_i[(b * HID + c) * LL + a]);
    } else if (u < WTB_SZ + D1WT_SZ) {
        int v = u - WTB_SZ;
        int c = v & 63, j = v >> 6;
        d1wT_all[i * D1WT_SZ + v] = deg1_w[(size_t)i * D1WT_SZ + c * 128 + j];
    } else {
        int v = u - WTB_SZ - D1WT_SZ;
        int c = v & 63, a = (v >> 6) & 15, ty = v >> 10;
        float s = 0.f;
        for (int b = 0; b < HID; ++b)
            s += bond_emb[i * 4 * HID + ty * HID + b] * w_i[(b * HID + c) * LL + a];
        ge_all[i * GE_SZ + v] = s;
    }
}

// ============================ per-layer kernels =============================
__global__ void k_init_h(const int* __restrict__ node_feat,
                         const float* __restrict__ atom_emb,
                         float* __restrict__ h) {
    int t = blockIdx.x * blockDim.x + threadIdx.x;
    if (t >= NN * HID) return;
    int n = t >> 6, c = t & 63;
    h[t] = atom_emb[node_feat[n] * HID + c];
}

// MFMA GEMM with 4-way M-group B-reuse; last block copies ge tail rows into g
__global__ void __launch_bounds__(256) k_gemm_g_mfma(
        const float* __restrict__ h,
        const unsigned short* __restrict__ wtB,
        const float* __restrict__ ge_i,
        unsigned short* __restrict__ g) {
    if (blockIdx.x == GEMM_BLOCKS) {
        for (int t = threadIdx.x; t < GE_SZ; t += 256)
            g[(size_t)(GE_BASE + (t >> 6)) * HID + (t & 63)] = f2bf(ge_i[t]);
        return;
    }
    int wave = threadIdx.x >> 6;
    int lane = threadIdx.x & 63;
    int mg4 = blockIdx.x * 4 + wave;
    if (mg4 * 4 >= MGRPS) return;
    int mrow = lane & 15;
    int kgrp = lane >> 4;

    bf16x8 A0[4], A1[4];
    bool valid[4];
    #pragma unroll
    for (int i = 0; i < 4; ++i) {
        int mgrp = mg4 * 4 + i;
        valid[i] = (mgrp < MGRPS);
        if (valid[i]) {
            const float* hrow = h + ((size_t)mgrp * 16 + mrow) * HID;
            float4 f0 = *(const float4*)(hrow + kgrp * 8);
            float4 f1 = *(const float4*)(hrow + kgrp * 8 + 4);
            float4 f2 = *(const float4*)(hrow + 32 + kgrp * 8);
            float4 f3 = *(const float4*)(hrow + 32 + kgrp * 8 + 4);
            bf16x8 a0, a1;
            a0[0] = (short)f2bf(f0.x); a0[1] = (short)f2bf(f0.y);
            a0[2] = (short)f2bf(f0.z); a0[3] = (short)f2bf(f0.w);
            a0[4] = (short)f2bf(f1.x); a0[5] = (short)f2bf(f1.y);
            a0[6] = (short)f2bf(f1.z); a0[7] = (short)f2bf(f1.w);
            a1[0] = (short)f2bf(f2.x); a1[1] = (short)f2bf(f2.y);
            a1[2] = (short)f2bf(f2.z); a1[3] = (short)f2bf(f2.w);
            a1[4] = (short)f2bf(f3.x); a1[5] = (short)f2bf(f3.y);
            a1[6] = (short)f2bf(f3.z); a1[7] = (short)f2bf(f3.w);
            A0[i] = a0; A1[i] = a1;
        } else {
            bf16x8 z;
            #pragma unroll
            for (int tt = 0; tt < 8; ++tt) z[tt] = 0;
            A0[i] = z; A1[i] = z;
        }
    }

    const unsigned short* bp = wtB + (size_t)mrow * HID + kgrp * 8;
    unsigned short* gp[4];
    #pragma unroll
    for (int i = 0; i < 4; ++i)
        gp[i] = g + (size_t)((mg4 * 4 + i) * 16 + kgrp * 4) * 1024 + mrow;

    for (int ntile = 0; ntile < 64; ++ntile) {
        bf16x8 b0 = *(const bf16x8*)(bp);
        bf16x8 b1 = *(const bf16x8*)(bp + 32);
        #pragma unroll
        for (int i = 0; i < 4; ++i) {
            if (!valid[i]) continue;
            f32x4 acc = {0.f, 0.f, 0.f, 0.f};
            acc = __builtin_amdgcn_mfma_f32_16x16x32_bf16(A0[i], b0, acc, 0, 0, 0);
            acc = __builtin_amdgcn_mfma_f32_16x16x32_bf16(A1[i], b1, acc, 0, 0, 0);
            #pragma unroll
            for (int r = 0; r < 4; ++r)
                gp[i][(size_t)r * 1024 + ntile * 16] = f2bf(acc[r]);
        }
        bp += 16 * HID;
    }
}

// ===== gather q: one wave per d; lane owns channel pair; halves take even/odd
// entries (dword g loads, 4 streams/lane = 8 entries in flight per wave) ======
__global__ void __launch_bounds__(256) k_gather_q(
        const int* __restrict__ qstart, const uint2* __restrict__ ent,
        const unsigned short* __restrict__ g,
        const float* __restrict__ bias_i, float* __restrict__ qrelu) {
    int wid = (blockIdx.x * 256 + threadIdx.x) >> 6;
    if (wid >= DDIM) return;
    int lane = threadIdx.x & 63;
    int half = lane >> 5, lp = lane & 31;
    float ax0 = 0.f, ay0 = 0.f, ax1 = 0.f, ay1 = 0.f;
    float ax2 = 0.f, ay2 = 0.f, ax3 = 0.f, ay3 = 0.f;
    int j = qstart[wid], je = qstart[wid + 1];
    for (; j + 7 < je; j += 8) {
        uint2 e0 = ent[j + half];
        uint2 e1 = ent[j + 2 + half];
        uint2 e2 = ent[j + 4 + half];
        uint2 e3 = ent[j + 6 + half];
        unsigned g0 = *(const unsigned*)(g + (size_t)e0.x * HID + 2 * lp);
        unsigned g1 = *(const unsigned*)(g + (size_t)e1.x * HID + 2 * lp);
        unsigned g2 = *(const unsigned*)(g + (size_t)e2.x * HID + 2 * lp);
        unsigned g3 = *(const unsigned*)(g + (size_t)e3.x * HID + 2 * lp);
        float v0 = __uint_as_float(e0.y), v1 = __uint_as_float(e1.y);
        float v2 = __uint_as_float(e2.y), v3 = __uint_as_float(e3.y);
        ax0 += v0 * bf2f((unsigned short)(g0 & 0xffffu));
        ay0 += v0 * bf2f((unsigned short)(g0 >> 16));
        ax1 += v1 * bf2f((unsigned short)(g1 & 0xffffu));
        ay1 += v1 * bf2f((unsigned short)(g1 >> 16));
        ax2 += v2 * bf2f((unsigned short)(g2 & 0xffffu));
        ay2 += v2 * bf2f((unsigned short)(g2 >> 16));
        ax3 += v3 * bf2f((unsigned short)(g3 & 0xffffu));
        ay3 += v3 * bf2f((unsigned short)(g3 >> 16));
    }
    for (; j + half < je; j += 2) {
        uint2 e0 = ent[j + half];
        unsigned g0 = *(const unsigned*)(g + (size_t)e0.x * HID + 2 * lp);
        float v0 = __uint_as_float(e0.y);
        ax1 += v0 * bf2f((unsigned short)(g0 & 0xffffu));
        ay1 += v0 * bf2f((unsigned short)(g0 >> 16));
    }
    float qx = (ax0 + ax1) + (ax2 + ax3);
    float qy = (ay0 + ay1) + (ay2 + ay3);
    qx += __shfl(qx, lane ^ 32, 64);
    qy += __shfl(qy, lane ^ 32, 64);
    if (half == 0) {
        float2 bias2 = *(const float2*)(bias_i + 2 * lp);
        float2 o = { fmaxf(qx + bias2.x, 0.f), fmaxf(qy + bias2.y, 0.f) };
        *(float2*)(qrelu + (size_t)wid * HID + 2 * lp) = o;
    }
}

// ===== pool-gather + degree gate (round-5 proven shape) =====================
__global__ void __launch_bounds__(256) k_pool_gate(
        const int* __restrict__ pstart, const uint2* __restrict__ pent,
        const float* __restrict__ qrelu, const float* __restrict__ degs,
        const float* __restrict__ d0w, const float* __restrict__ d0b,
        const float* __restrict__ d1wT, const float* __restrict__ d1b,
        float* __restrict__ h) {
    int wid = (blockIdx.x * 256 + threadIdx.x) >> 6;
    if (wid >= NN) return;
    int c = threadIdx.x & 63;
    float acc0 = 0.f, acc1 = 0.f;
    int j = pstart[wid], e = pstart[wid + 1];
    for (; j + 1 < e; j += 2) {
        uint2 e0 = pent[j], e1 = pent[j + 1];
        acc0 += __uint_as_float(e0.y) * qrelu[(size_t)e0.x * HID + c];
        acc1 += __uint_as_float(e1.y) * qrelu[(size_t)e1.x * HID + c];
    }
    if (j < e) {
        uint2 e0 = pent[j];
        acc0 += __uint_as_float(e0.y) * qrelu[(size_t)e0.x * HID + c];
    }
    float acc = acc0 + acc1;
    float deg = degs[wid];
    float rv0 = fmaxf(deg * d0w[c]      + d0b[c],      0.f);
    float rv1 = fmaxf(deg * d0w[64 + c] + d0b[64 + c], 0.f);
    float gf = d1b[c];
    #pragma unroll 8
    for (int j2 = 0; j2 < 64; ++j2) {
        float f0 = __shfl(rv0, j2, 64);
        float f1 = __shfl(rv1, j2, 64);
        gf += d1wT[j2 * HID + c] * f0 + d1wT[(64 + j2) * HID + c] * f1;
    }
    h[(size_t)wid * HID + c] = acc * gf;
}

// ============================== epilogue ====================================
__global__ void k_reduce(const float* __restrict__ h, float* __restrict__ partial_red) {
    __shared__ float lds[256];
    int tid = threadIdx.x;
    float s = 0.f;
    for (int idx = blockIdx.x * 256 + tid; idx < NN * HID; idx += gridDim.x * 256)
        s += h[idx];
    lds[tid] = s;
    __syncthreads();
    if (tid < 64)
        partial_red[blockIdx.x * 64 + tid] = lds[tid] + lds[tid + 64] + lds[tid + 128] + lds[tid + 192];
}

__global__ void k_final(const float* __restrict__ partial_red,
                        const float* __restrict__ fw,
                        const float* __restrict__ fb, float* __restrict__ out) {
    int lane = threadIdx.x;
    float s = 0.f;
    for (int b = 0; b < 256; ++b) s += partial_red[b * 64 + lane];
    float v = s * (1.0f / NN) * fw[lane];
    for (int off = 32; off; off >>= 1) v += __shfl_down(v, off, 64);
    if (lane == 0) out[0] = v + fb[0];
}

// ============================================================================
extern "C" void kernel_launch(void* const* d_in, const int* in_sizes, int n_in,
                              void* d_out, int out_size, void* d_ws, size_t ws_size,
                              hipStream_t stream) {
    const int*   node_feat = (const int*)d_in[0];
    const int*   edge_feat = (const int*)d_in[1];
    const float* degs      = (const float*)d_in[2];
    const int*   n2p_rows  = (const int*)d_in[3];
    const int*   n2p_cols  = (const int*)d_in[4];
    const float* n2p_vals  = (const float*)d_in[5];
    const int*   e2p_rows  = (const int*)d_in[6];
    const int*   e2p_cols  = (const int*)d_in[7];
    const float* e2p_vals  = (const float*)d_in[8];
    const int*   pool_rows = (const int*)d_in[9];
    const int*   pool_cols = (const int*)d_in[10];
    const float* pool_vals = (const float*)d_in[11];
    const float* atom_emb  = (const float*)d_in[13];
    const float* bond_emb  = (const float*)d_in[14];
    const float* weights   = (const float*)d_in[15];
    const float* bias      = (const float*)d_in[16];
    const float* deg0_w    = (const float*)d_in[17];
    const float* deg0_b    = (const float*)d_in[18];
    const float* deg1_w    = (const float*)d_in[19];
    const float* deg1_b    = (const float*)d_in[20];
    const float* final_w   = (const float*)d_in[21];
    const float* final_b   = (const float*)d_in[22];
    float* out = (float*)d_out;

    char* wsb = (char*)d_ws;
    size_t off = 0;
    auto alloc = [&](size_t bytes) -> void* {
        void* ptr = wsb + off;
        off += (bytes + 255) & ~(size_t)255;
        return ptr;
    };
    float*          h        = (float*)alloc((size_t)NN * HID * 4);               // 12.8 MB
    unsigned short* g        = (unsigned short*)alloc((size_t)GROWS * HID * 2);   // 102.4 MB
    float*          qrelu    = (float*)alloc((size_t)DDIM * HID * 4);             // 25.6 MB
    unsigned short* wtB_all  = (unsigned short*)alloc((size_t)NLAYERS * WTB_SZ * 2);
    float*          d1wT_all = (float*)alloc((size_t)NLAYERS * D1WT_SZ * 4);
    float*          ge_all   = (float*)alloc((size_t)NLAYERS * GE_SZ * 4);
    float*          partial_red = (float*)alloc(256 * 64 * 4);
    int*   start_all = (int*)alloc((size_t)(NBINS + 1) * 4);
    int*   partial   = (int*)alloc(512 * 4);
    uint2* ent_all   = (uint2*)alloc((size_t)TOTENT * 8);     // 20 MB

    // rank_all (10 MB) + cnt (0.6 MB) overlay the idle qrelu buffer during CSR
    int* rank_all = (int*)qrelu;
    int* cnt      = rank_all + TOTENT;   // needs 2.5M + 150K ints = 10.6 MB < 25.6 MB

    // ---------------- CSR build (shared across layers) ----------------------
    k_zero_i<<<(NBINS + 255) / 256, 256, 0, stream>>>(cnt, NBINS);
    k_hist_all<<<(TOTENT + 255) / 256, 256, 0, stream>>>(n2p_rows, e2p_rows, pool_rows,
                                                         cnt, rank_all);
    k_scan_block<<<(NBINS + 1023) / 1024, 256, 0, stream>>>(cnt, start_all, partial, NBINS);
    k_scan_partial<<<1, 64, 0, stream>>>(partial, (NBINS + 1023) / 1024);
    k_scan_add<<<(NBINS + 255) / 256, 256, 0, stream>>>(start_all, partial, NBINS);
    k_set_term<<<1, 1, 0, stream>>>(start_all);
    k_fill_all<<<(TOTENT + 255) / 256, 256, 0, stream>>>(n2p_rows, n2p_cols, n2p_vals,
                                                         e2p_rows, e2p_cols, e2p_vals,
                                                         pool_rows, pool_cols, pool_vals,
                                                         edge_feat, start_all, rank_all, ent_all);

    // ---------------- prep + init -------------------------------------------
    k_prep_all<<<(NLAYERS * PER_LAYER + 255) / 256, 256, 0, stream>>>(
        weights, bond_emb, deg1_w, wtB_all, d1wT_all, ge_all);
    k_init_h<<<(NN * HID + 255) / 256, 256, 0, stream>>>(node_feat, atom_emb, h);

    // ---------------- layers ------------------------------------------------
    for (int i = 0; i < NLAYERS; ++i) {
        k_gemm_g_mfma<<<GEMM_BLOCKS + 1, 256, 0, stream>>>(
            h, wtB_all + (size_t)i * WTB_SZ, ge_all + (size_t)i * GE_SZ, g);
        k_gather_q<<<(DDIM + 3) / 4, 256, 0, stream>>>(
            start_all, ent_all, g, bias + i * HID, qrelu);
        k_pool_gate<<<(NN + 3) / 4, 256, 0, stream>>>(
            start_all + DDIM, ent_all, qrelu, degs,
            deg0_w + i * 2 * HID, deg0_b + i * 2 * HID,
            d1wT_all + (size_t)i * D1WT_SZ, deg1_b + i * HID, h);
    }

    k_reduce<<<256, 256, 0, stream>>>(h, partial_red);
    k_final<<<1, 64, 0, stream>>>(partial_red, final_w, final_b, out);
}

// Round 9
// 768.633 us; speedup vs baseline: 2.7452x; 1.2413x over previous
//
#include <hip/hip_runtime.h>

#define HID 64
#define LL 16
#define NLAYERS 4
#define NN 50000
#define NE 200000
#define PRR 1600000
#define DDIM 100000        // PRR / LL
#define MGRPS 3125         // NN / 16
#define GE_BASE 800000     // ge rows appended to g after NN*16 rows
#define GROWS 800064
#define N2P_CNT PRR
#define E2P_CNT (PRR / 2)
#define POOL_CNT DDIM
#define TOTENT (N2P_CNT + E2P_CNT + POOL_CNT)   // 2.5M
#define NBINS (DDIM + NN)                        // 150000
#define GEMM_BLOCKS 196    // ceil(3125/16); block GEMM_BLOCKS does ge tail copy

typedef __attribute__((ext_vector_type(8))) short bf16x8;
typedef __attribute__((ext_vector_type(4))) float f32x4;

__device__ __forceinline__ unsigned short f2bf(float x) {
    unsigned u = __float_as_uint(x);
    unsigned r = (u + 0x7fffu + ((u >> 16) & 1u)) >> 16;
    return (unsigned short)r;
}
__device__ __forceinline__ float bf2f(unsigned short v) {
    return __uint_as_float((unsigned)v << 16);
}

// ======================= CSR build (once per call) ==========================
__global__ void k_zero_i(int* __restrict__ b, int n) {
    int t = blockIdx.x * blockDim.x + threadIdx.x;
    if (t < n) b[t] = 0;
}
__global__ void k_set_term(int* __restrict__ start_all) {
    start_all[NBINS] = TOTENT;
}

__global__ void k_hist_all(const int* __restrict__ n2p_rows,
                           const int* __restrict__ e2p_rows,
                           const int* __restrict__ pool_rows,
                           int* __restrict__ cnt, int* __restrict__ rank_all) {
    int k = blockIdx.x * blockDim.x + threadIdx.x;
    if (k >= TOTENT) return;
    int bin;
    if (k < N2P_CNT) {
        bin = n2p_rows[k] >> 4;
    } else if (k < N2P_CNT + E2P_CNT) {
        bin = e2p_rows[k - N2P_CNT] >> 4;
    } else {
        bin = DDIM + pool_rows[k - N2P_CNT - E2P_CNT];
    }
    rank_all[k] = atomicAdd(&cnt[bin], 1);
}

__global__ void __launch_bounds__(256) k_scan_block(const int* __restrict__ cnt,
                                                    int* __restrict__ excl,
                                                    int* __restrict__ partial, int B) {
    __shared__ int lds[1024];
    int tid = threadIdx.x;
    int base = blockIdx.x * 1024;
    int self[4];
    #pragma unroll
    for (int r = 0; r < 4; ++r) {
        int i = r * 256 + tid;
        self[r] = (base + i < B) ? cnt[base + i] : 0;
        lds[i] = self[r];
    }
    __syncthreads();
    for (int off = 1; off < 1024; off <<= 1) {
        int v[4];
        #pragma unroll
        for (int r = 0; r < 4; ++r) {
            int i = r * 256 + tid;
            v[r] = (i >= off) ? lds[i - off] : 0;
        }
        __syncthreads();
        #pragma unroll
        for (int r = 0; r < 4; ++r) lds[r * 256 + tid] += v[r];
        __syncthreads();
    }
    #pragma unroll
    for (int r = 0; r < 4; ++r) {
        int i = r * 256 + tid;
        if (base + i < B) excl[base + i] = lds[i] - self[r];
    }
    if (tid == 0) partial[blockIdx.x] = lds[1023];
}

__global__ void k_scan_partial(int* __restrict__ partial, int nb) {
    if (threadIdx.x == 0) {
        int run = 0;
        for (int i = 0; i < nb; ++i) { int v = partial[i]; partial[i] = run; run += v; }
    }
}

__global__ void k_scan_add(int* __restrict__ excl, const int* __restrict__ partial, int B) {
    int i = blockIdx.x * blockDim.x + threadIdx.x;
    if (i < B) excl[i] += partial[i >> 10];
}

// unified fill: q-bin payload = g row index; pool-bin payload = d column.
__global__ void k_fill_all(const int* __restrict__ n2p_rows, const int* __restrict__ n2p_cols,
                           const float* __restrict__ n2p_vals,
                           const int* __restrict__ e2p_rows, const int* __restrict__ e2p_cols,
                           const float* __restrict__ e2p_vals,
                           const int* __restrict__ pool_rows, const int* __restrict__ pool_cols,
                           const float* __restrict__ pool_vals,
                           const int* __restrict__ edge_feat,
                           const int* __restrict__ start_all, const int* __restrict__ rank_all,
                           uint2* __restrict__ ent_all) {
    int k = blockIdx.x * blockDim.x + threadIdx.x;
    if (k >= TOTENT) return;
    int bin; unsigned pay; float val;
    if (k < N2P_CNT) {
        int r = n2p_rows[k];
        bin = r >> 4;
        pay = (unsigned)n2p_cols[k] * 16u + (unsigned)(r & 15);
        val = n2p_vals[k];
    } else if (k < N2P_CNT + E2P_CNT) {
        int kk = k - N2P_CNT;
        int r = e2p_rows[kk];
        bin = r >> 4;
        pay = (unsigned)GE_BASE + (unsigned)edge_feat[e2p_cols[kk]] * 16u + (unsigned)(r & 15);
        val = e2p_vals[kk];
    } else {
        int kk = k - N2P_CNT - E2P_CNT;
        bin = DDIM + pool_rows[kk];
        pay = (unsigned)pool_cols[kk];
        val = pool_vals[kk];
    }
    ent_all[start_all[bin] + rank_all[k]] = make_uint2(pay, __float_as_uint(val));
}

// ===================== upfront prep for ALL layers ==========================
#define WTB_SZ (LL * HID * HID)     // 65536
#define D1W_SZ (128 * HID)          // 8192
#define GE_SZ (4 * LL * HID)        // 4096
#define PER_LAYER (WTB_SZ + D1W_SZ + GE_SZ)   // 77824

__global__ void k_prep_all(const float* __restrict__ weights,
                           const float* __restrict__ bond_emb,
                           const float* __restrict__ deg1_w,
                           unsigned short* __restrict__ wtB_all,
                           unsigned short* __restrict__ d1wB_all,
                           float* __restrict__ ge_all) {
    int t = blockIdx.x * blockDim.x + threadIdx.x;
    if (t >= NLAYERS * PER_LAYER) return;
    int i = t / PER_LAYER;
    int u = t % PER_LAYER;
    const float* w_i = weights + (size_t)i * WTB_SZ;
    if (u < WTB_SZ) {
        int b = u & 63, N = u >> 6;
        int a = N >> 6, c = N & 63;
        wtB_all[(size_t)i * WTB_SZ + u] = f2bf(w_i[(b * HID + c) * LL + a]);
    } else if (u < WTB_SZ + D1W_SZ) {
        int v = u - WTB_SZ;
        // d1wB: [c][j] bf16 — deg1_w's native layout
        d1wB_all[i * D1W_SZ + v] = f2bf(deg1_w[(size_t)i * D1W_SZ + v]);
    } else {
        int v = u - WTB_SZ - D1W_SZ;
        int c = v & 63, a = (v >> 6) & 15, ty = v >> 10;
        float s = 0.f;
        for (int b = 0; b < HID; ++b)
            s += bond_emb[i * 4 * HID + ty * HID + b] * w_i[(b * HID + c) * LL + a];
        ge_all[i * GE_SZ + v] = s;
    }
}

// ============================ per-layer kernels =============================
__global__ void k_init_h(const int* __restrict__ node_feat,
                         const float* __restrict__ atom_emb,
                         float* __restrict__ h) {
    int t = blockIdx.x * blockDim.x + threadIdx.x;
    if (t >= NN * HID) return;
    int n = t >> 6, c = t & 63;
    h[t] = atom_emb[node_feat[n] * HID + c];
}

// MFMA GEMM with 4-way M-group B-reuse; last block copies ge tail rows into g
__global__ void __launch_bounds__(256) k_gemm_g_mfma(
        const float* __restrict__ h,
        const unsigned short* __restrict__ wtB,
        const float* __restrict__ ge_i,
        unsigned short* __restrict__ g) {
    if (blockIdx.x == GEMM_BLOCKS) {
        for (int t = threadIdx.x; t < GE_SZ; t += 256)
            g[(size_t)(GE_BASE + (t >> 6)) * HID + (t & 63)] = f2bf(ge_i[t]);
        return;
    }
    int wave = threadIdx.x >> 6;
    int lane = threadIdx.x & 63;
    int mg4 = blockIdx.x * 4 + wave;
    if (mg4 * 4 >= MGRPS) return;
    int mrow = lane & 15;
    int kgrp = lane >> 4;

    bf16x8 A0[4], A1[4];
    bool valid[4];
    #pragma unroll
    for (int i = 0; i < 4; ++i) {
        int mgrp = mg4 * 4 + i;
        valid[i] = (mgrp < MGRPS);
        if (valid[i]) {
            const float* hrow = h + ((size_t)mgrp * 16 + mrow) * HID;
            float4 f0 = *(const float4*)(hrow + kgrp * 8);
            float4 f1 = *(const float4*)(hrow + kgrp * 8 + 4);
            float4 f2 = *(const float4*)(hrow + 32 + kgrp * 8);
            float4 f3 = *(const float4*)(hrow + 32 + kgrp * 8 + 4);
            bf16x8 a0, a1;
            a0[0] = (short)f2bf(f0.x); a0[1] = (short)f2bf(f0.y);
            a0[2] = (short)f2bf(f0.z); a0[3] = (short)f2bf(f0.w);
            a0[4] = (short)f2bf(f1.x); a0[5] = (short)f2bf(f1.y);
            a0[6] = (short)f2bf(f1.z); a0[7] = (short)f2bf(f1.w);
            a1[0] = (short)f2bf(f2.x); a1[1] = (short)f2bf(f2.y);
            a1[2] = (short)f2bf(f2.z); a1[3] = (short)f2bf(f2.w);
            a1[4] = (short)f2bf(f3.x); a1[5] = (short)f2bf(f3.y);
            a1[6] = (short)f2bf(f3.z); a1[7] = (short)f2bf(f3.w);
            A0[i] = a0; A1[i] = a1;
        } else {
            bf16x8 z;
            #pragma unroll
            for (int tt = 0; tt < 8; ++tt) z[tt] = 0;
            A0[i] = z; A1[i] = z;
        }
    }

    const unsigned short* bp = wtB + (size_t)mrow * HID + kgrp * 8;
    unsigned short* gp[4];
    #pragma unroll
    for (int i = 0; i < 4; ++i)
        gp[i] = g + (size_t)((mg4 * 4 + i) * 16 + kgrp * 4) * 1024 + mrow;

    for (int ntile = 0; ntile < 64; ++ntile) {
        bf16x8 b0 = *(const bf16x8*)(bp);
        bf16x8 b1 = *(const bf16x8*)(bp + 32);
        #pragma unroll
        for (int i = 0; i < 4; ++i) {
            if (!valid[i]) continue;
            f32x4 acc = {0.f, 0.f, 0.f, 0.f};
            acc = __builtin_amdgcn_mfma_f32_16x16x32_bf16(A0[i], b0, acc, 0, 0, 0);
            acc = __builtin_amdgcn_mfma_f32_16x16x32_bf16(A1[i], b1, acc, 0, 0, 0);
            #pragma unroll
            for (int r = 0; r < 4; ++r)
                gp[i][(size_t)r * 1024 + ntile * 16] = f2bf(acc[r]);
        }
        bp += 16 * HID;
    }
}

// ===== gate precompute via MFMA: gate[n][c] = sum_j relu(deg*d0w[j]+d0b[j])*d1w[c][j] + d1b[c]
__global__ void __launch_bounds__(256) k_gate_mfma(
        const float* __restrict__ degs,
        const float* __restrict__ d0w,              // [128]
        const float* __restrict__ d0b,              // [128]
        const unsigned short* __restrict__ d1wB,    // [64][128] bf16
        const float* __restrict__ d1b,              // [64]
        float* __restrict__ gate) {
    int wave = threadIdx.x >> 6, lane = threadIdx.x & 63;
    int mgrp = blockIdx.x * 4 + wave;
    if (mgrp >= MGRPS) return;
    int mrow = lane & 15, kgrp = lane >> 4;
    float deg = degs[mgrp * 16 + mrow];

    f32x4 acc[4];
    #pragma unroll
    for (int t = 0; t < 4; ++t) acc[t] = (f32x4){0.f, 0.f, 0.f, 0.f};

    #pragma unroll
    for (int s = 0; s < 4; ++s) {
        bf16x8 A;
        #pragma unroll
        for (int jj = 0; jj < 8; ++jj) {
            int k = s * 32 + kgrp * 8 + jj;
            A[jj] = (short)f2bf(fmaxf(deg * d0w[k] + d0b[k], 0.f));
        }
        #pragma unroll
        for (int t = 0; t < 4; ++t) {
            bf16x8 B = *(const bf16x8*)(d1wB + (t * 16 + mrow) * 128 + s * 32 + kgrp * 8);
            acc[t] = __builtin_amdgcn_mfma_f32_16x16x32_bf16(A, B, acc[t], 0, 0, 0);
        }
    }
    #pragma unroll
    for (int t = 0; t < 4; ++t) {
        float bb = d1b[t * 16 + mrow];
        #pragma unroll
        for (int r = 0; r < 4; ++r)
            gate[(size_t)(mgrp * 16 + kgrp * 4 + r) * HID + t * 16 + mrow] = acc[t][r] + bb;
    }
}

// ===== gather q: one wave per d; lane owns channel pair; halves take even/odd
// entries; 8 load streams/lane (16 entries in flight per wave) ================
__global__ void __launch_bounds__(256) k_gather_q(
        const int* __restrict__ qstart, const uint2* __restrict__ ent,
        const unsigned short* __restrict__ g,
        const float* __restrict__ bias_i, float* __restrict__ qrelu) {
    int wid = (blockIdx.x * 256 + threadIdx.x) >> 6;
    if (wid >= DDIM) return;
    int lane = threadIdx.x & 63;
    int half = lane >> 5, lp = lane & 31;
    float ax[8], ay[8];
    #pragma unroll
    for (int t = 0; t < 8; ++t) { ax[t] = 0.f; ay[t] = 0.f; }
    int j = qstart[wid], je = qstart[wid + 1];
    for (; j + 15 < je; j += 16) {
        #pragma unroll
        for (int t = 0; t < 8; ++t) {
            uint2 e = ent[j + 2 * t + half];
            unsigned gv = *(const unsigned*)(g + (size_t)e.x * HID + 2 * lp);
            float v = __uint_as_float(e.y);
            ax[t] += v * bf2f((unsigned short)(gv & 0xffffu));
            ay[t] += v * bf2f((unsigned short)(gv >> 16));
        }
    }
    for (; j + 7 < je; j += 8) {
        #pragma unroll
        for (int t = 0; t < 4; ++t) {
            uint2 e = ent[j + 2 * t + half];
            unsigned gv = *(const unsigned*)(g + (size_t)e.x * HID + 2 * lp);
            float v = __uint_as_float(e.y);
            ax[t] += v * bf2f((unsigned short)(gv & 0xffffu));
            ay[t] += v * bf2f((unsigned short)(gv >> 16));
        }
    }
    for (; j + half < je; j += 2) {
        uint2 e = ent[j + half];
        unsigned gv = *(const unsigned*)(g + (size_t)e.x * HID + 2 * lp);
        float v = __uint_as_float(e.y);
        ax[4] += v * bf2f((unsigned short)(gv & 0xffffu));
        ay[4] += v * bf2f((unsigned short)(gv >> 16));
    }
    float qx = ((ax[0] + ax[1]) + (ax[2] + ax[3])) + ((ax[4] + ax[5]) + (ax[6] + ax[7]));
    float qy = ((ay[0] + ay[1]) + (ay[2] + ay[3])) + ((ay[4] + ay[5]) + (ay[6] + ay[7]));
    qx += __shfl(qx, lane ^ 32, 64);
    qy += __shfl(qy, lane ^ 32, 64);
    if (half == 0) {
        float2 bias2 = *(const float2*)(bias_i + 2 * lp);
        float2 o = { fmaxf(qx + bias2.x, 0.f), fmaxf(qy + bias2.y, 0.f) };
        *(float2*)(qrelu + (size_t)wid * HID + 2 * lp) = o;
    }
}

// ===== pool-gather × precomputed gate ========================================
__global__ void __launch_bounds__(256) k_pool_gate(
        const int* __restrict__ pstart, const uint2* __restrict__ pent,
        const float* __restrict__ qrelu, const float* __restrict__ gate,
        float* __restrict__ h) {
    int wid = (blockIdx.x * 256 + threadIdx.x) >> 6;
    if (wid >= NN) return;
    int c = threadIdx.x & 63;
    float acc0 = 0.f, acc1 = 0.f;
    int j = pstart[wid], e = pstart[wid + 1];
    for (; j + 1 < e; j += 2) {
        uint2 e0 = pent[j], e1 = pent[j + 1];
        acc0 += __uint_as_float(e0.y) * qrelu[(size_t)e0.x * HID + c];
        acc1 += __uint_as_float(e1.y) * qrelu[(size_t)e1.x * HID + c];
    }
    if (j < e) {
        uint2 e0 = pent[j];
        acc0 += __uint_as_float(e0.y) * qrelu[(size_t)e0.x * HID + c];
    }
    h[(size_t)wid * HID + c] = (acc0 + acc1) * gate[(size_t)wid * HID + c];
}

// ============================== epilogue ====================================
__global__ void k_reduce(const float* __restrict__ h, float* __restrict__ partial_red) {
    __shared__ float lds[256];
    int tid = threadIdx.x;
    float s = 0.f;
    for (int idx = blockIdx.x * 256 + tid; idx < NN * HID; idx += gridDim.x * 256)
        s += h[idx];
    lds[tid] = s;
    __syncthreads();
    if (tid < 64)
        partial_red[blockIdx.x * 64 + tid] = lds[tid] + lds[tid + 64] + lds[tid + 128] + lds[tid + 192];
}

__global__ void k_final(const float* __restrict__ partial_red,
                        const float* __restrict__ fw,
                        const float* __restrict__ fb, float* __restrict__ out) {
    int lane = threadIdx.x;
    float s = 0.f;
    for (int b = 0; b < 256; ++b) s += partial_red[b * 64 + lane];
    float v = s * (1.0f / NN) * fw[lane];
    for (int off = 32; off; off >>= 1) v += __shfl_down(v, off, 64);
    if (lane == 0) out[0] = v + fb[0];
}

// ============================================================================
extern "C" void kernel_launch(void* const* d_in, const int* in_sizes, int n_in,
                              void* d_out, int out_size, void* d_ws, size_t ws_size,
                              hipStream_t stream) {
    const int*   node_feat = (const int*)d_in[0];
    const int*   edge_feat = (const int*)d_in[1];
    const float* degs      = (const float*)d_in[2];
    const int*   n2p_rows  = (const int*)d_in[3];
    const int*   n2p_cols  = (const int*)d_in[4];
    const float* n2p_vals  = (const float*)d_in[5];
    const int*   e2p_rows  = (const int*)d_in[6];
    const int*   e2p_cols  = (const int*)d_in[7];
    const float* e2p_vals  = (const float*)d_in[8];
    const int*   pool_rows = (const int*)d_in[9];
    const int*   pool_cols = (const int*)d_in[10];
    const float* pool_vals = (const float*)d_in[11];
    const float* atom_emb  = (const float*)d_in[13];
    const float* bond_emb  = (const float*)d_in[14];
    const float* weights   = (const float*)d_in[15];
    const float* bias      = (const float*)d_in[16];
    const float* deg0_w    = (const float*)d_in[17];
    const float* deg0_b    = (const float*)d_in[18];
    const float* deg1_w    = (const float*)d_in[19];
    const float* deg1_b    = (const float*)d_in[20];
    const float* final_w   = (const float*)d_in[21];
    const float* final_b   = (const float*)d_in[22];
    float* out = (float*)d_out;

    char* wsb = (char*)d_ws;
    size_t off = 0;
    auto alloc = [&](size_t bytes) -> void* {
        void* ptr = wsb + off;
        off += (bytes + 255) & ~(size_t)255;
        return ptr;
    };
    float*          h        = (float*)alloc((size_t)NN * HID * 4);               // 12.8 MB
    unsigned short* g        = (unsigned short*)alloc((size_t)GROWS * HID * 2);   // 102.4 MB
    float*          qrelu    = (float*)alloc((size_t)DDIM * HID * 4);             // 25.6 MB
    float*          gate     = (float*)alloc((size_t)NN * HID * 4);               // 12.8 MB
    unsigned short* wtB_all  = (unsigned short*)alloc((size_t)NLAYERS * WTB_SZ * 2);
    unsigned short* d1wB_all = (unsigned short*)alloc((size_t)NLAYERS * D1W_SZ * 2);
    float*          ge_all   = (float*)alloc((size_t)NLAYERS * GE_SZ * 4);
    float*          partial_red = (float*)alloc(256 * 64 * 4);
    int*   start_all = (int*)alloc((size_t)(NBINS + 1) * 4);
    int*   partial   = (int*)alloc(512 * 4);
    uint2* ent_all   = (uint2*)alloc((size_t)TOTENT * 8);     // 20 MB

    // rank_all (10 MB) + cnt (0.6 MB) overlay the idle qrelu buffer during CSR
    int* rank_all = (int*)qrelu;
    int* cnt      = rank_all + TOTENT;

    // ---------------- CSR build (shared across layers) ----------------------
    k_zero_i<<<(NBINS + 255) / 256, 256, 0, stream>>>(cnt, NBINS);
    k_hist_all<<<(TOTENT + 255) / 256, 256, 0, stream>>>(n2p_rows, e2p_rows, pool_rows,
                                                         cnt, rank_all);
    k_scan_block<<<(NBINS + 1023) / 1024, 256, 0, stream>>>(cnt, start_all, partial, NBINS);
    k_scan_partial<<<1, 64, 0, stream>>>(partial, (NBINS + 1023) / 1024);
    k_scan_add<<<(NBINS + 255) / 256, 256, 0, stream>>>(start_all, partial, NBINS);
    k_set_term<<<1, 1, 0, stream>>>(start_all);
    k_fill_all<<<(TOTENT + 255) / 256, 256, 0, stream>>>(n2p_rows, n2p_cols, n2p_vals,
                                                         e2p_rows, e2p_cols, e2p_vals,
                                                         pool_rows, pool_cols, pool_vals,
                                                         edge_feat, start_all, rank_all, ent_all);

    // ---------------- prep + init -------------------------------------------
    k_prep_all<<<(NLAYERS * PER_LAYER + 255) / 256, 256, 0, stream>>>(
        weights, bond_emb, deg1_w, wtB_all, d1wB_all, ge_all);
    k_init_h<<<(NN * HID + 255) / 256, 256, 0, stream>>>(node_feat, atom_emb, h);

    // ---------------- layers ------------------------------------------------
    for (int i = 0; i < NLAYERS; ++i) {
        k_gemm_g_mfma<<<GEMM_BLOCKS + 1, 256, 0, stream>>>(
            h, wtB_all + (size_t)i * WTB_SZ, ge_all + (size_t)i * GE_SZ, g);
        k_gate_mfma<<<(MGRPS + 3) / 4, 256, 0, stream>>>(
            degs, deg0_w + i * 2 * HID, deg0_b + i * 2 * HID,
            d1wB_all + (size_t)i * D1W_SZ, deg1_b + i * HID, gate);
        k_gather_q<<<(DDIM + 3) / 4, 256, 0, stream>>>(
            start_all, ent_all, g, bias + i * HID, qrelu);
        k_pool_gate<<<(NN + 3) / 4, 256, 0, stream>>>(
            start_all + DDIM, ent_all, qrelu, gate, h);
    }

    k_reduce<<<256, 256, 0, stream>>>(h, partial_red);
    k_final<<<1, 64, 0, stream>>>(partial_red, final_w, final_b, out);
}

// Round 10
// 667.349 us; speedup vs baseline: 3.1619x; 1.1518x over previous
//
#include <hip/hip_runtime.h>

#define HID 64
#define LL 16
#define NLAYERS 4
#define NN 50000
#define NE 200000
#define PRR 1600000
#define DDIM 100000        // PRR / LL
#define MGRPS 3125         // NN / 16
#define GE_BASE 800000     // ge rows appended to g after NN*16 rows
#define GROWS 800064
#define N2P_CNT PRR
#define E2P_CNT (PRR / 2)
#define POOL_CNT DDIM
#define TOTENT (N2P_CNT + E2P_CNT + POOL_CNT)   // 2.5M
#define NBINS (DDIM + NN)                        // 150000
#define QCAP 64
#define PCAP 16
#define GEMM_BLOCKS 196    // ceil(3125/16)
#define GATE_BLOCKS 782    // ceil(3125/4)

typedef __attribute__((ext_vector_type(8))) short bf16x8;
typedef __attribute__((ext_vector_type(4))) float f32x4;

__device__ __forceinline__ unsigned short f2bf(float x) {
    unsigned u = __float_as_uint(x);
    unsigned r = (u + 0x7fffu + ((u >> 16) & 1u)) >> 16;
    return (unsigned short)r;
}
__device__ __forceinline__ float bf2f(unsigned short v) {
    return __uint_as_float((unsigned)v << 16);
}

// ======================= CSR build (once per call) ==========================
__global__ void k_zero_i(int* __restrict__ b, int n) {
    int t = blockIdx.x * blockDim.x + threadIdx.x;
    if (t < n) b[t] = 0;
}

// single-pass padded fill: slot = atomicAdd(cnt[bin]); write into bin*CAP+slot
__global__ void k_fill_padded(
        const int* __restrict__ n2p_rows, const int* __restrict__ n2p_cols,
        const float* __restrict__ n2p_vals,
        const int* __restrict__ e2p_rows, const int* __restrict__ e2p_cols,
        const float* __restrict__ e2p_vals,
        const int* __restrict__ pool_rows, const int* __restrict__ pool_cols,
        const float* __restrict__ pool_vals,
        const int* __restrict__ edge_feat,
        int* __restrict__ cnt, uint2* __restrict__ entq, uint2* __restrict__ entp) {
    int k = blockIdx.x * blockDim.x + threadIdx.x;
    if (k >= TOTENT) return;
    if (k < N2P_CNT) {
        int r = n2p_rows[k];
        int bin = r >> 4;
        unsigned pay = (unsigned)n2p_cols[k] * 16u + (unsigned)(r & 15);
        int slot = atomicAdd(&cnt[bin], 1);
        slot = min(slot, QCAP - 1);
        entq[(size_t)bin * QCAP + slot] = make_uint2(pay, __float_as_uint(n2p_vals[k]));
    } else if (k < N2P_CNT + E2P_CNT) {
        int kk = k - N2P_CNT;
        int r = e2p_rows[kk];
        int bin = r >> 4;
        unsigned pay = (unsigned)GE_BASE + (unsigned)edge_feat[e2p_cols[kk]] * 16u
                     + (unsigned)(r & 15);
        int slot = atomicAdd(&cnt[bin], 1);
        slot = min(slot, QCAP - 1);
        entq[(size_t)bin * QCAP + slot] = make_uint2(pay, __float_as_uint(e2p_vals[kk]));
    } else {
        int kk = k - N2P_CNT - E2P_CNT;
        int bin = pool_rows[kk];
        int slot = atomicAdd(&cnt[DDIM + bin], 1);
        slot = min(slot, PCAP - 1);
        entp[(size_t)bin * PCAP + slot] =
            make_uint2((unsigned)pool_cols[kk], __float_as_uint(pool_vals[kk]));
    }
}

// ===================== upfront prep + h init (merged) =======================
#define WTB_SZ (LL * HID * HID)     // 65536
#define D1W_SZ (128 * HID)          // 8192
#define GE_SZ (4 * LL * HID)        // 4096
#define PER_LAYER (WTB_SZ + D1W_SZ + GE_SZ)   // 77824
#define PREP_BLOCKS ((NLAYERS * PER_LAYER + 255) / 256)   // 1216

__global__ void k_prep_init(const float* __restrict__ weights,
                            const float* __restrict__ bond_emb,
                            const float* __restrict__ deg1_w,
                            const int* __restrict__ node_feat,
                            const float* __restrict__ atom_emb,
                            unsigned short* __restrict__ wtB_all,
                            unsigned short* __restrict__ d1wB_all,
                            float* __restrict__ ge_all,
                            float* __restrict__ h) {
    int bid = blockIdx.x;
    if (bid < PREP_BLOCKS) {
        int t = bid * 256 + threadIdx.x;
        if (t >= NLAYERS * PER_LAYER) return;
        int i = t / PER_LAYER;
        int u = t % PER_LAYER;
        const float* w_i = weights + (size_t)i * WTB_SZ;
        if (u < WTB_SZ) {
            int b = u & 63, N = u >> 6;
            int a = N >> 6, c = N & 63;
            wtB_all[(size_t)i * WTB_SZ + u] = f2bf(w_i[(b * HID + c) * LL + a]);
        } else if (u < WTB_SZ + D1W_SZ) {
            int v = u - WTB_SZ;
            d1wB_all[i * D1W_SZ + v] = f2bf(deg1_w[(size_t)i * D1W_SZ + v]);
        } else {
            int v = u - WTB_SZ - D1W_SZ;
            int c = v & 63, a = (v >> 6) & 15, ty = v >> 10;
            float s = 0.f;
            for (int b = 0; b < HID; ++b)
                s += bond_emb[i * 4 * HID + ty * HID + b] * w_i[(b * HID + c) * LL + a];
            ge_all[i * GE_SZ + v] = s;
        }
    } else {
        int t = (bid - PREP_BLOCKS) * 256 + threadIdx.x;
        if (t >= NN * HID) return;
        int n = t >> 6, c = t & 63;
        h[t] = atom_emb[node_feat[n] * HID + c];
    }
}

// ======== merged per-layer matrix work: gemm | ge-copy | gate (by block) ====
__global__ void __launch_bounds__(256) k_gemm_gate(
        const float* __restrict__ h,
        const unsigned short* __restrict__ wtB,
        const float* __restrict__ ge_i,
        unsigned short* __restrict__ g,
        const float* __restrict__ degs,
        const float* __restrict__ d0w, const float* __restrict__ d0b,
        const unsigned short* __restrict__ d1wB, const float* __restrict__ d1b,
        float* __restrict__ gate) {
    int bid = blockIdx.x;
    int wave = threadIdx.x >> 6;
    int lane = threadIdx.x & 63;
    int mrow = lane & 15;
    int kgrp = lane >> 4;

    if (bid < GEMM_BLOCKS) {
        int mg4 = bid * 4 + wave;
        if (mg4 * 4 >= MGRPS) return;
        bf16x8 A0[4], A1[4];
        bool valid[4];
        #pragma unroll
        for (int i = 0; i < 4; ++i) {
            int mgrp = mg4 * 4 + i;
            valid[i] = (mgrp < MGRPS);
            if (valid[i]) {
                const float* hrow = h + ((size_t)mgrp * 16 + mrow) * HID;
                float4 f0 = *(const float4*)(hrow + kgrp * 8);
                float4 f1 = *(const float4*)(hrow + kgrp * 8 + 4);
                float4 f2 = *(const float4*)(hrow + 32 + kgrp * 8);
                float4 f3 = *(const float4*)(hrow + 32 + kgrp * 8 + 4);
                bf16x8 a0, a1;
                a0[0] = (short)f2bf(f0.x); a0[1] = (short)f2bf(f0.y);
                a0[2] = (short)f2bf(f0.z); a0[3] = (short)f2bf(f0.w);
                a0[4] = (short)f2bf(f1.x); a0[5] = (short)f2bf(f1.y);
                a0[6] = (short)f2bf(f1.z); a0[7] = (short)f2bf(f1.w);
                a1[0] = (short)f2bf(f2.x); a1[1] = (short)f2bf(f2.y);
                a1[2] = (short)f2bf(f2.z); a1[3] = (short)f2bf(f2.w);
                a1[4] = (short)f2bf(f3.x); a1[5] = (short)f2bf(f3.y);
                a1[6] = (short)f2bf(f3.z); a1[7] = (short)f2bf(f3.w);
                A0[i] = a0; A1[i] = a1;
            } else {
                bf16x8 z;
                #pragma unroll
                for (int tt = 0; tt < 8; ++tt) z[tt] = 0;
                A0[i] = z; A1[i] = z;
            }
        }
        const unsigned short* bp = wtB + (size_t)mrow * HID + kgrp * 8;
        unsigned short* gp[4];
        #pragma unroll
        for (int i = 0; i < 4; ++i)
            gp[i] = g + (size_t)((mg4 * 4 + i) * 16 + kgrp * 4) * 1024 + mrow;
        for (int ntile = 0; ntile < 64; ++ntile) {
            bf16x8 b0 = *(const bf16x8*)(bp);
            bf16x8 b1 = *(const bf16x8*)(bp + 32);
            #pragma unroll
            for (int i = 0; i < 4; ++i) {
                if (!valid[i]) continue;
                f32x4 acc = {0.f, 0.f, 0.f, 0.f};
                acc = __builtin_amdgcn_mfma_f32_16x16x32_bf16(A0[i], b0, acc, 0, 0, 0);
                acc = __builtin_amdgcn_mfma_f32_16x16x32_bf16(A1[i], b1, acc, 0, 0, 0);
                #pragma unroll
                for (int r = 0; r < 4; ++r)
                    gp[i][(size_t)r * 1024 + ntile * 16] = f2bf(acc[r]);
            }
            bp += 16 * HID;
        }
    } else if (bid == GEMM_BLOCKS) {
        for (int t = threadIdx.x; t < GE_SZ; t += 256)
            g[(size_t)(GE_BASE + (t >> 6)) * HID + (t & 63)] = f2bf(ge_i[t]);
    } else {
        int mgrp = (bid - GEMM_BLOCKS - 1) * 4 + wave;
        if (mgrp >= MGRPS) return;
        float deg = degs[mgrp * 16 + mrow];
        f32x4 acc[4];
        #pragma unroll
        for (int t = 0; t < 4; ++t) acc[t] = (f32x4){0.f, 0.f, 0.f, 0.f};
        #pragma unroll
        for (int s = 0; s < 4; ++s) {
            bf16x8 A;
            #pragma unroll
            for (int jj = 0; jj < 8; ++jj) {
                int k = s * 32 + kgrp * 8 + jj;
                A[jj] = (short)f2bf(fmaxf(deg * d0w[k] + d0b[k], 0.f));
            }
            #pragma unroll
            for (int t = 0; t < 4; ++t) {
                bf16x8 B = *(const bf16x8*)(d1wB + (t * 16 + mrow) * 128 + s * 32 + kgrp * 8);
                acc[t] = __builtin_amdgcn_mfma_f32_16x16x32_bf16(A, B, acc[t], 0, 0, 0);
            }
        }
        #pragma unroll
        for (int t = 0; t < 4; ++t) {
            float bb = d1b[t * 16 + mrow];
            #pragma unroll
            for (int r = 0; r < 4; ++r)
                gate[(size_t)(mgrp * 16 + kgrp * 4 + r) * HID + t * 16 + mrow] = acc[t][r] + bb;
        }
    }
}

// ===== gather q: wave per d; 16-lane groups, lane owns 4 channels (8B loads);
// 4 groups x 4 streams = 16 entries in flight ================================
__global__ void __launch_bounds__(256) k_gather_q(
        const int* __restrict__ cnt, const uint2* __restrict__ entq,
        const unsigned short* __restrict__ g,
        const float* __restrict__ bias_i, float* __restrict__ qrelu) {
    int wid = (blockIdx.x * 256 + threadIdx.x) >> 6;
    if (wid >= DDIM) return;
    int lane = threadIdx.x & 63;
    int lp = lane & 15, grp = lane >> 4;
    int len = min(cnt[wid], QCAP);
    const uint2* eb = entq + (size_t)wid * QCAP;
    float ac[4][4];
    #pragma unroll
    for (int t = 0; t < 4; ++t)
        #pragma unroll
        for (int q = 0; q < 4; ++q) ac[t][q] = 0.f;
    int j = 0;
    for (; j + 16 <= len; j += 16) {
        #pragma unroll
        for (int t = 0; t < 4; ++t) {
            uint2 e = eb[j + 4 * t + grp];
            uint2 gv = *(const uint2*)(g + (size_t)e.x * HID + 4 * lp);
            float v = __uint_as_float(e.y);
            ac[t][0] += v * bf2f((unsigned short)(gv.x & 0xffffu));
            ac[t][1] += v * bf2f((unsigned short)(gv.x >> 16));
            ac[t][2] += v * bf2f((unsigned short)(gv.y & 0xffffu));
            ac[t][3] += v * bf2f((unsigned short)(gv.y >> 16));
        }
    }
    for (; j < len; j += 4) {
        if (j + grp < len) {
            uint2 e = eb[j + grp];
            uint2 gv = *(const uint2*)(g + (size_t)e.x * HID + 4 * lp);
            float v = __uint_as_float(e.y);
            ac[0][0] += v * bf2f((unsigned short)(gv.x & 0xffffu));
            ac[0][1] += v * bf2f((unsigned short)(gv.x >> 16));
            ac[0][2] += v * bf2f((unsigned short)(gv.y & 0xffffu));
            ac[0][3] += v * bf2f((unsigned short)(gv.y >> 16));
        }
    }
    float s0 = (ac[0][0] + ac[1][0]) + (ac[2][0] + ac[3][0]);
    float s1 = (ac[0][1] + ac[1][1]) + (ac[2][1] + ac[3][1]);
    float s2 = (ac[0][2] + ac[1][2]) + (ac[2][2] + ac[3][2]);
    float s3 = (ac[0][3] + ac[1][3]) + (ac[2][3] + ac[3][3]);
    s0 += __shfl_xor(s0, 16, 64); s0 += __shfl_xor(s0, 32, 64);
    s1 += __shfl_xor(s1, 16, 64); s1 += __shfl_xor(s1, 32, 64);
    s2 += __shfl_xor(s2, 16, 64); s2 += __shfl_xor(s2, 32, 64);
    s3 += __shfl_xor(s3, 16, 64); s3 += __shfl_xor(s3, 32, 64);
    if (grp == 0) {
        float4 b4 = *(const float4*)(bias_i + 4 * lp);
        float4 o = { fmaxf(s0 + b4.x, 0.f), fmaxf(s1 + b4.y, 0.f),
                     fmaxf(s2 + b4.z, 0.f), fmaxf(s3 + b4.w, 0.f) };
        *(float4*)(qrelu + (size_t)wid * HID + 4 * lp) = o;
    }
}

// ===== pool-gather x gate: wave per node, 16-lane groups, float4 loads ======
__global__ void __launch_bounds__(256) k_pool_gate(
        const int* __restrict__ cnt, const uint2* __restrict__ entp,
        const float* __restrict__ qrelu, const float* __restrict__ gate,
        float* __restrict__ h) {
    int wid = (blockIdx.x * 256 + threadIdx.x) >> 6;
    if (wid >= NN) return;
    int lane = threadIdx.x & 63;
    int lp = lane & 15, grp = lane >> 4;
    int len = min(cnt[DDIM + wid], PCAP);
    const uint2* eb = entp + (size_t)wid * PCAP;
    float s0 = 0.f, s1 = 0.f, s2 = 0.f, s3 = 0.f;
    for (int j = 0; j < len; j += 4) {
        if (j + grp < len) {
            uint2 e = eb[j + grp];
            float4 qv = *(const float4*)(qrelu + (size_t)e.x * HID + 4 * lp);
            float v = __uint_as_float(e.y);
            s0 += v * qv.x; s1 += v * qv.y; s2 += v * qv.z; s3 += v * qv.w;
        }
    }
    s0 += __shfl_xor(s0, 16, 64); s0 += __shfl_xor(s0, 32, 64);
    s1 += __shfl_xor(s1, 16, 64); s1 += __shfl_xor(s1, 32, 64);
    s2 += __shfl_xor(s2, 16, 64); s2 += __shfl_xor(s2, 32, 64);
    s3 += __shfl_xor(s3, 16, 64); s3 += __shfl_xor(s3, 32, 64);
    if (grp == 0) {
        float4 gt = *(const float4*)(gate + (size_t)wid * HID + 4 * lp);
        float4 o = { s0 * gt.x, s1 * gt.y, s2 * gt.z, s3 * gt.w };
        *(float4*)(h + (size_t)wid * HID + 4 * lp) = o;
    }
}

// ============================== epilogue ====================================
__global__ void k_reduce(const float* __restrict__ h, float* __restrict__ partial_red) {
    __shared__ float lds[256];
    int tid = threadIdx.x;
    float s = 0.f;
    for (int idx = blockIdx.x * 256 + tid; idx < NN * HID; idx += gridDim.x * 256)
        s += h[idx];
    lds[tid] = s;
    __syncthreads();
    if (tid < 64)
        partial_red[blockIdx.x * 64 + tid] = lds[tid] + lds[tid + 64] + lds[tid + 128] + lds[tid + 192];
}

__global__ void k_final(const float* __restrict__ partial_red,
                        const float* __restrict__ fw,
                        const float* __restrict__ fb, float* __restrict__ out) {
    int lane = threadIdx.x;
    float s = 0.f;
    for (int b = 0; b < 256; ++b) s += partial_red[b * 64 + lane];
    float v = s * (1.0f / NN) * fw[lane];
    for (int off = 32; off; off >>= 1) v += __shfl_down(v, off, 64);
    if (lane == 0) out[0] = v + fb[0];
}

// ============================================================================
extern "C" void kernel_launch(void* const* d_in, const int* in_sizes, int n_in,
                              void* d_out, int out_size, void* d_ws, size_t ws_size,
                              hipStream_t stream) {
    const int*   node_feat = (const int*)d_in[0];
    const int*   edge_feat = (const int*)d_in[1];
    const float* degs      = (const float*)d_in[2];
    const int*   n2p_rows  = (const int*)d_in[3];
    const int*   n2p_cols  = (const int*)d_in[4];
    const float* n2p_vals  = (const float*)d_in[5];
    const int*   e2p_rows  = (const int*)d_in[6];
    const int*   e2p_cols  = (const int*)d_in[7];
    const float* e2p_vals  = (const float*)d_in[8];
    const int*   pool_rows = (const int*)d_in[9];
    const int*   pool_cols = (const int*)d_in[10];
    const float* pool_vals = (const float*)d_in[11];
    const float* atom_emb  = (const float*)d_in[13];
    const float* bond_emb  = (const float*)d_in[14];
    const float* weights   = (const float*)d_in[15];
    const float* bias      = (const float*)d_in[16];
    const float* deg0_w    = (const float*)d_in[17];
    const float* deg0_b    = (const float*)d_in[18];
    const float* deg1_w    = (const float*)d_in[19];
    const float* deg1_b    = (const float*)d_in[20];
    const float* final_w   = (const float*)d_in[21];
    const float* final_b   = (const float*)d_in[22];
    float* out = (float*)d_out;

    char* wsb = (char*)d_ws;
    size_t off = 0;
    auto alloc = [&](size_t bytes) -> void* {
        void* ptr = wsb + off;
        off += (bytes + 255) & ~(size_t)255;
        return ptr;
    };
    float*          h        = (float*)alloc((size_t)NN * HID * 4);               // 12.8 MB
    unsigned short* g        = (unsigned short*)alloc((size_t)GROWS * HID * 2);   // 102.4 MB
    float*          qrelu    = (float*)alloc((size_t)DDIM * HID * 4);             // 25.6 MB
    float*          gate     = (float*)alloc((size_t)NN * HID * 4);               // 12.8 MB
    unsigned short* wtB_all  = (unsigned short*)alloc((size_t)NLAYERS * WTB_SZ * 2);
    unsigned short* d1wB_all = (unsigned short*)alloc((size_t)NLAYERS * D1W_SZ * 2);
    float*          ge_all   = (float*)alloc((size_t)NLAYERS * GE_SZ * 4);
    float*          partial_red = (float*)alloc(256 * 64 * 4);
    int*            cnt      = (int*)alloc((size_t)NBINS * 4);                    // 0.6 MB
    uint2*          entq     = (uint2*)alloc((size_t)DDIM * QCAP * 8);            // 51.2 MB
    uint2*          entp     = (uint2*)alloc((size_t)NN * PCAP * 8);              // 6.4 MB

    // ---------------- CSR build: zero + single fused pass --------------------
    k_zero_i<<<(NBINS + 255) / 256, 256, 0, stream>>>(cnt, NBINS);
    k_fill_padded<<<(TOTENT + 255) / 256, 256, 0, stream>>>(
        n2p_rows, n2p_cols, n2p_vals, e2p_rows, e2p_cols, e2p_vals,
        pool_rows, pool_cols, pool_vals, edge_feat, cnt, entq, entp);

    // ---------------- prep + init (merged) -----------------------------------
    int init_blocks = (NN * HID + 255) / 256;
    k_prep_init<<<PREP_BLOCKS + init_blocks, 256, 0, stream>>>(
        weights, bond_emb, deg1_w, node_feat, atom_emb,
        wtB_all, d1wB_all, ge_all, h);

    // ---------------- layers -------------------------------------------------
    for (int i = 0; i < NLAYERS; ++i) {
        k_gemm_gate<<<GEMM_BLOCKS + 1 + GATE_BLOCKS, 256, 0, stream>>>(
            h, wtB_all + (size_t)i * WTB_SZ, ge_all + (size_t)i * GE_SZ, g,
            degs, deg0_w + i * 2 * HID, deg0_b + i * 2 * HID,
            d1wB_all + (size_t)i * D1W_SZ, deg1_b + i * HID, gate);
        k_gather_q<<<(DDIM + 3) / 4, 256, 0, stream>>>(
            cnt, entq, g, bias + i * HID, qrelu);
        k_pool_gate<<<(NN + 3) / 4, 256, 0, stream>>>(
            cnt, entp, qrelu, gate, h);
    }

    k_reduce<<<256, 256, 0, stream>>>(h, partial_red);
    k_final<<<1, 64, 0, stream>>>(partial_red, final_w, final_b, out);
}